// Round 8
// baseline (222.730 us; speedup 1.0000x reference)
//
#include <hip/hip_runtime.h>
#include <hip/hip_fp16.h>
#include <math.h>

#define N_NODES   50000
#define N_EDGES   800000
#define IN_DIM    128
#define HID       64
#define OUT_DIM   128
#define N_GRAPHS  256
#define MAX_DEG   64      // ELL row stride; P(indeg>64) for Binomial(800k,1/50k) ~ 0
#define PARTS     8       // XCD count; blockIdx%8 -> XCD round-robin heuristic
#define PSIZE     (N_NODES / PARTS)
#define EPB       4096    // edges per build chunk (= 256 threads x 16 edges)
#define AGG_NPB   32      // nodes per agg block (4 waves x 8 octets)
#define GEMM_BLKS 782     // ceil(50000/64)

typedef _Float16 half8 __attribute__((ext_vector_type(8)));
typedef float floatx4 __attribute__((ext_vector_type(4)));

// ---------------- tiny pre-kernel: pack W1, W2 to fp16 B-fragments ----------------

__global__ __launch_bounds__(256) void k_prep_w(const float* __restrict__ W1, __half* __restrict__ Wt1,
                                                const float* __restrict__ W2, __half* __restrict__ Wt2) {
    int blk = blockIdx.x;
    if (blk < 4) {
        int idx = blk * 256 + threadIdx.x;   // 0..1023 = (128/8)*64
        int g = idx >> 6, n = idx & 63;
#pragma unroll
        for (int i = 0; i < 8; i++)
            Wt1[idx * 8 + i] = __float2half(W1[(8 * g + i) * 64 + n]);
    } else {
        int idx = (blk - 4) * 256 + threadIdx.x;   // 0..511 = (64/8)*64
        if (idx < 512) {
            int g = idx >> 6, n = idx & 63;
#pragma unroll
            for (int i = 0; i < 8; i++)
                Wt2[idx * 8 + i] = __float2half(W2[(8 * g + i) * 64 + n]);
        }
    }
}

// ---------------- fused: layer-1 GEMM (UNSCALED x@W1) || edge build ----------------

__global__ __launch_bounds__(256) void k_fused1(const float* __restrict__ A,
                                                const __half* __restrict__ Bp,
                                                __half* __restrict__ C,
                                                const int* __restrict__ src,
                                                const int* __restrict__ dst,
                                                int* __restrict__ deg,
                                                int* __restrict__ col) {
    if (blockIdx.x < GEMM_BLKS) {
        constexpr int K = IN_DIM, S = K / 32;
        int wv   = threadIdx.x >> 6;
        int lane = threadIdx.x & 63;
        int quad = lane >> 4, l15 = lane & 15;
        int row0 = blockIdx.x * 64 + wv * 16;
        if (row0 >= N_NODES) return;

        half8 bf[S][4];
#pragma unroll
        for (int s = 0; s < S; s++)
#pragma unroll
            for (int j = 0; j < 4; j++)
                bf[s][j] = *(const half8*)(Bp + ((size_t)((4 * s + quad) * 64 + 16 * j + l15)) * 8);

        floatx4 acc[4];
#pragma unroll
        for (int j = 0; j < 4; j++) acc[j] = 0.f;

        int arow = row0 + l15;
#pragma unroll
        for (int s = 0; s < S; s++) {
            float4 xa = *(const float4*)(A + (size_t)arow * K + 32 * s + quad * 8);
            float4 xb = *(const float4*)(A + (size_t)arow * K + 32 * s + quad * 8 + 4);
            half8 af;
            af[0] = (_Float16)xa.x; af[1] = (_Float16)xa.y;
            af[2] = (_Float16)xa.z; af[3] = (_Float16)xa.w;
            af[4] = (_Float16)xb.x; af[5] = (_Float16)xb.y;
            af[6] = (_Float16)xb.z; af[7] = (_Float16)xb.w;
#pragma unroll
            for (int j = 0; j < 4; j++)
                acc[j] = __builtin_amdgcn_mfma_f32_16x16x32_f16(af, bf[s][j], acc[j], 0, 0, 0);
        }
#pragma unroll
        for (int j = 0; j < 4; j++)
#pragma unroll
            for (int r = 0; r < 4; r++)
                C[(size_t)(row0 + quad * 4 + r) * 64 + 16 * j + l15] = __float2half(acc[j][r]);
    } else {
        int bid   = blockIdx.x - GEMM_BLKS;
        int p     = bid & (PARTS - 1);
        int chunk = bid >> 3;
        int e0    = chunk * EPB + threadIdx.x * 16;
        if (e0 + 16 > N_EDGES) return;
        int lo = p * PSIZE, hi = lo + PSIZE;

        int dd[16], ss[16];
        const int4* d4 = (const int4*)(dst + e0);
        const int4* s4 = (const int4*)(src + e0);
#pragma unroll
        for (int j = 0; j < 4; j++) {
            int4 q = d4[j];
            dd[4 * j + 0] = q.x; dd[4 * j + 1] = q.y;
            dd[4 * j + 2] = q.z; dd[4 * j + 3] = q.w;
        }
#pragma unroll
        for (int j = 0; j < 4; j++) {
            int4 q = s4[j];
            ss[4 * j + 0] = q.x; ss[4 * j + 1] = q.y;
            ss[4 * j + 2] = q.z; ss[4 * j + 3] = q.w;
        }

        int pos[16];
#pragma unroll
        for (int j = 0; j < 16; j++) {
            pos[j] = -1;
            if (dd[j] >= lo && dd[j] < hi) pos[j] = atomicAdd(&deg[dd[j]], 1);
        }
#pragma unroll
        for (int j = 0; j < 16; j++) {
            if (pos[j] >= 0 && pos[j] < MAX_DEG)
                col[(size_t)dd[j] * MAX_DEG + pos[j]] = ss[j];
        }
    }
}

// ---------------- helpers ----------------

__device__ __forceinline__ void fma8(float* acc, uint4 v, float w) {
    const __half2* h = (const __half2*)&v;
#pragma unroll
    for (int j = 0; j < 4; j++) {
        acc[2 * j]     += w * __low2float(h[j]);
        acc[2 * j + 1] += w * __high2float(h[j]);
    }
}

// ---------------- FUSED layer-1 aggregate + gelu + layer-2 GEMM ----------------
// Gather unscaled T=x@W1 with dinv[s] weights, gelu epilogue, stage 32x64 h1*dv rows
// to LDS, then each wave MFMAs a 16-row x 32-col quadrant with Wt2 -> OUT = (dv.h1)@W2.
// Kills the p global round-trip and the separate mfma2 dispatch.

__global__ __launch_bounds__(256) void k_agg_mm(const __half* __restrict__ T,
                                                const int* __restrict__ col,
                                                const int* __restrict__ indeg,
                                                const float* __restrict__ b,
                                                const __half* __restrict__ Bp,
                                                __half* __restrict__ OUT) {
    __shared__ int cols[AGG_NPB][MAX_DEG + 1];
    __shared__ int sdeg[AGG_NPB];
    __shared__ __half p_tile[AGG_NPB][72];   // stride 72 halves (144B): conflict-minimal
    int base = blockIdx.x * AGG_NPB;

    if (threadIdx.x < AGG_NPB) {
        int g = base + threadIdx.x;
        int dg0 = (g < N_NODES) ? indeg[g] : 0;
        sdeg[threadIdx.x] = dg0 > MAX_DEG ? MAX_DEG : dg0;
    }
    __syncthreads();

    for (int idx = threadIdx.x; idx < AGG_NPB * MAX_DEG; idx += 256) {
        int r = idx >> 6, j = idx & 63;
        if (j < sdeg[r]) cols[r][j] = col[(size_t)(base + r) * MAX_DEG + j];
    }
    __syncthreads();

    int lane = threadIdx.x & 63;
    int wv   = threadIdx.x >> 6;
    int q = lane >> 3, t = lane & 7;     // octet = node, t = 16-byte chunk
    int local = wv * 8 + q;
    int d = base + local;

    if (d < N_NODES) {                   // predicated (all lanes reach barrier below)
        int dg = sdeg[local];
        float dv = rsqrtf((float)(indeg[d] + 1));

        float acc[8];
#pragma unroll
        for (int j = 0; j < 8; j++) acc[j] = 0.f;
        fma8(acc, *(const uint4*)(T + (size_t)d * HID + t * 8), dv);   // self term

        const int* cl = cols[local];
        int i = 0;
        for (; i + 4 <= dg; i += 4) {
            int s0 = cl[i], s1 = cl[i + 1], s2 = cl[i + 2], s3 = cl[i + 3];
            uint4 v0 = *(const uint4*)(T + (size_t)s0 * HID + t * 8);
            uint4 v1 = *(const uint4*)(T + (size_t)s1 * HID + t * 8);
            uint4 v2 = *(const uint4*)(T + (size_t)s2 * HID + t * 8);
            uint4 v3 = *(const uint4*)(T + (size_t)s3 * HID + t * 8);
            float w0 = rsqrtf((float)(indeg[s0] + 1));
            float w1 = rsqrtf((float)(indeg[s1] + 1));
            float w2 = rsqrtf((float)(indeg[s2] + 1));
            float w3 = rsqrtf((float)(indeg[s3] + 1));
            fma8(acc, v0, w0); fma8(acc, v1, w1); fma8(acc, v2, w2); fma8(acc, v3, w3);
        }
        for (; i < dg; i++) {
            int s = cl[i];
            fma8(acc, *(const uint4*)(T + (size_t)s * HID + t * 8), rsqrtf((float)(indeg[s] + 1)));
        }

        // epilogue: o = dv * gelu(acc*dv + b); store h1*dv to LDS as fp16 (A-rows for W2)
        half8 hrow;
#pragma unroll
        for (int j = 0; j < 8; j++) {
            float v = acc[j] * dv + b[t * 8 + j];
            float u2 = 0.7978845608028654f * (v + 0.044715f * v * v * v);
            float th = 1.0f - 2.0f / (__expf(2.0f * u2) + 1.0f);
            hrow[j] = (_Float16)(0.5f * v * (1.0f + th) * dv);
        }
        *(half8*)&p_tile[local][t * 8] = hrow;
    }
    __syncthreads();

    // ---- MFMA phase: wave wv computes rows [rows16,rows16+16) x cols [32*(wv&1),+32) ----
    int quad = lane >> 4, l15 = lane & 15;
    int rows16 = (wv >> 1) * 16;
    int j0 = (wv & 1) * 2;
    if (base + rows16 < N_NODES) {
        half8 bfr[2][2];
#pragma unroll
        for (int s = 0; s < 2; s++)
#pragma unroll
            for (int jj = 0; jj < 2; jj++)
                bfr[s][jj] = *(const half8*)(Bp + ((size_t)((4 * s + quad) * 64 + 16 * (j0 + jj) + l15)) * 8);

        floatx4 acc2[2];
        acc2[0] = 0.f; acc2[1] = 0.f;
#pragma unroll
        for (int s = 0; s < 2; s++) {
            half8 a = *(const half8*)&p_tile[rows16 + l15][s * 32 + quad * 8];
            acc2[0] = __builtin_amdgcn_mfma_f32_16x16x32_f16(a, bfr[s][0], acc2[0], 0, 0, 0);
            acc2[1] = __builtin_amdgcn_mfma_f32_16x16x32_f16(a, bfr[s][1], acc2[1], 0, 0, 0);
        }
#pragma unroll
        for (int jj = 0; jj < 2; jj++)
#pragma unroll
            for (int r = 0; r < 4; r++) {
                int row = base + rows16 + quad * 4 + r;
                if (row < N_NODES)
                    OUT[(size_t)row * 64 + 16 * (j0 + jj) + l15] = __float2half(acc2[jj][r]);
            }
    }
}

// ---------------- aggregation layers 2/3 (inline rsqrt dv; inputs pre-scaled) ----------------
// mode 0: OUT = dv * gelu(acc*dv + b) * dv ; mode 1: OUT = acc*dv

__global__ __launch_bounds__(256) void k_agg(const __half* __restrict__ T,
                                             const int* __restrict__ col,
                                             const int* __restrict__ indeg,
                                             const float* __restrict__ b,
                                             __half* __restrict__ OUT, int mode) {
    __shared__ int cols[AGG_NPB][MAX_DEG + 1];
    __shared__ int sdeg[AGG_NPB];
    int base = blockIdx.x * AGG_NPB;

    if (threadIdx.x < AGG_NPB) {
        int g = base + threadIdx.x;
        int dg0 = (g < N_NODES) ? indeg[g] : 0;
        sdeg[threadIdx.x] = dg0 > MAX_DEG ? MAX_DEG : dg0;
    }
    __syncthreads();

    for (int idx = threadIdx.x; idx < AGG_NPB * MAX_DEG; idx += 256) {
        int r = idx >> 6, j = idx & 63;
        if (j < sdeg[r]) cols[r][j] = col[(size_t)(base + r) * MAX_DEG + j];
    }
    __syncthreads();

    int lane = threadIdx.x & 63;
    int wv   = threadIdx.x >> 6;
    int q = lane >> 3, t = lane & 7;
    int local = wv * 8 + q;
    int d = base + local;
    if (d >= N_NODES) return;

    int dg = sdeg[local];
    float dv = rsqrtf((float)(indeg[d] + 1));

    float acc[8];
#pragma unroll
    for (int j = 0; j < 8; j++) acc[j] = 0.f;
    fma8(acc, *(const uint4*)(T + (size_t)d * HID + t * 8), 1.0f);

    const int* cl = cols[local];
    int i = 0;
    for (; i + 4 <= dg; i += 4) {
        int s0 = cl[i], s1 = cl[i + 1], s2 = cl[i + 2], s3 = cl[i + 3];
        uint4 v0 = *(const uint4*)(T + (size_t)s0 * HID + t * 8);
        uint4 v1 = *(const uint4*)(T + (size_t)s1 * HID + t * 8);
        uint4 v2 = *(const uint4*)(T + (size_t)s2 * HID + t * 8);
        uint4 v3 = *(const uint4*)(T + (size_t)s3 * HID + t * 8);
        fma8(acc, v0, 1.f); fma8(acc, v1, 1.f); fma8(acc, v2, 1.f); fma8(acc, v3, 1.f);
    }
    for (; i < dg; i++) {
        int s = cl[i];
        fma8(acc, *(const uint4*)(T + (size_t)s * HID + t * 8), 1.f);
    }

    float o[8];
#pragma unroll
    for (int j = 0; j < 8; j++) o[j] = acc[j] * dv;
    if (mode == 0) {
#pragma unroll
        for (int j = 0; j < 8; j++) {
            float v = o[j] + b[t * 8 + j];
            float u2 = 0.7978845608028654f * (v + 0.044715f * v * v * v);
            float th = 1.0f - 2.0f / (__expf(2.0f * u2) + 1.0f);
            o[j] = 0.5f * v * (1.0f + th) * dv;
        }
    }
    __half2 hh[4];
#pragma unroll
    for (int j = 0; j < 4; j++) hh[j] = __floats2half2_rn(o[2 * j], o[2 * j + 1]);
    *(uint4*)(OUT + (size_t)d * HID + t * 8) = *(uint4*)hh;
}

// ---------------- fused segmented mean-pool + final GEMM (batch is SORTED) ----------------

__global__ __launch_bounds__(256) void k_pool_out(const __half* __restrict__ A,
                                                  const int* __restrict__ batch,
                                                  const float* __restrict__ W3,
                                                  const float* __restrict__ b3,
                                                  float* __restrict__ out) {
    int g = blockIdx.x;
    int lo = 0, hi = N_NODES;
    while (lo < hi) { int m = (lo + hi) >> 1; if (batch[m] < g) lo = m + 1; else hi = m; }
    int lo2 = lo, hi2 = N_NODES;
    while (lo2 < hi2) { int m = (lo2 + hi2) >> 1; if (batch[m] < g + 1) lo2 = m + 1; else hi2 = m; }
    int start = lo, end = lo2;

    int lane = threadIdx.x & 63;
    int wave = threadIdx.x >> 6;
    float acc = 0.f;
    for (int n = start + wave; n < end; n += 4)
        acc += __half2float(A[(size_t)n * HID + lane]);

    __shared__ float part[4][HID];
    __shared__ float pooled[HID];
    part[wave][lane] = acc;
    __syncthreads();
    if (threadIdx.x < HID)
        pooled[threadIdx.x] = part[0][threadIdx.x] + part[1][threadIdx.x] +
                              part[2][threadIdx.x] + part[3][threadIdx.x];
    __syncthreads();

    if (threadIdx.x < OUT_DIM) {
        float cntf = (float)(end - start);
        float inv = 1.0f / fmaxf(cntf, 1.0f);
        float s = 0.f;
#pragma unroll
        for (int k = 0; k < HID; k++) s += pooled[k] * W3[k * OUT_DIM + threadIdx.x];
        out[g * OUT_DIM + threadIdx.x] = (s + cntf * b3[threadIdx.x]) * inv;
    }
}

// ---------------- launch ----------------

extern "C" void kernel_launch(void* const* d_in, const int* in_sizes, int n_in,
                              void* d_out, int out_size, void* d_ws, size_t ws_size,
                              hipStream_t stream) {
    const float* x     = (const float*)d_in[0];
    const int*   ei    = (const int*)d_in[1];
    const int*   batch = (const int*)d_in[2];
    const float* W1    = (const float*)d_in[4];
    const float* b1    = (const float*)d_in[5];
    const float* W2    = (const float*)d_in[6];
    const float* b2    = (const float*)d_in[7];
    const float* W3    = (const float*)d_in[8];
    const float* b3    = (const float*)d_in[9];
    float* out = (float*)d_out;

    const int* esrc = ei;
    const int* edst = ei + N_EDGES;

    // workspace layout
    int*    deg  = (int*)d_ws;                           // 50000 (zeroed; doubles as cursor)
    int*    col  = deg + N_NODES;                        // 3.2M ints (12.8 MB)
    __half* t    = (__half*)(col + (size_t)N_NODES * MAX_DEG);   // 3.2M halves
    __half* p    = t + (size_t)N_NODES * HID;                    // 3.2M halves
    __half* Wt1  = p + (size_t)N_NODES * HID;                    // 8192 halves
    __half* Wt2  = Wt1 + IN_DIM * HID;                           // 4096 halves

    (void)hipMemsetAsync(deg, 0, (size_t)N_NODES * 4, stream);

    const int CHUNKS = (N_EDGES + EPB - 1) / EPB;        // 196
    const int AB = (N_NODES + AGG_NPB - 1) / AGG_NPB;    // 1563 agg blocks

    // pack weights, then fused layer-1 GEMM || edge build
    k_prep_w<<<6, 256, 0, stream>>>(W1, Wt1, W2, Wt2);
    k_fused1<<<GEMM_BLKS + CHUNKS * PARTS, 256, 0, stream>>>(x, Wt1, t, esrc, edst, deg, col);

    // layer-1 agg + gelu + layer-2 GEMM fused:  p = (dv .* gelu(conv1)) @ W2
    k_agg_mm<<<AB, 256, 0, stream>>>(t, col, deg, b1, Wt2, p);
    // layer 2 aggregate
    k_agg<<<AB, 256, 0, stream>>>(p, col, deg, b2, t, 0);
    // layer 3 aggregate (width 64, pre-GEMM)
    k_agg<<<AB, 256, 0, stream>>>(t, col, deg, b3, p, 1);
    // fused mean-pool + 64->128 GEMM
    k_pool_out<<<N_GRAPHS, 256, 0, stream>>>(p, batch, W3, b3, out);
}